// Round 5
// baseline (756.680 us; speedup 1.0000x reference)
//
#include <hip/hip_runtime.h>
#include <cstdint>
#include <cstddef>

#define NROWS 4096
#define DIM   1024            // elements per row; also BYTES per fp8 row
#define TWON  8192
#define INV_T 2.0f
// exp(2.0) = exp(sim_rr / T) for the masked diagonal (rows are unit-norm)
#define EXP_DIAG 7.38905609893065f
#define NT    528             // # of 256x256 tiles covering the upper triangle
#define SCALE1 0x7F7F7F7F     // 4x E8M0 unity scales (127 -> 2^0)

typedef float floatx4 __attribute__((ext_vector_type(4)));
typedef int   intx4   __attribute__((ext_vector_type(4)));
typedef int   intx8   __attribute__((ext_vector_type(8)));

union F8 { intx8 v8; intx4 v4[2]; };

__device__ __forceinline__ void gload16(const uint8_t* g, uint8_t* l) {
  __builtin_amdgcn_global_load_lds(
      (const __attribute__((address_space(1))) void*)g,
      (__attribute__((address_space(3))) void*)l,
      16, 0, 0);
}

// -- kernel 1: normalize -> fp8 reps, fp32 pos dot, zero denom/cnt ------------
// UNCHANGED so the total-time delta attributes to simsum.
__global__ __launch_bounds__(256) void normpos_kernel(
    const float* __restrict__ emb_i, const float* __restrict__ emb_j,
    uint8_t* __restrict__ reps, float* __restrict__ denom,
    float* __restrict__ pos, unsigned int* __restrict__ cnt) {
  const int t    = threadIdx.x;
  const int lane = t & 63;
  const int wave = t >> 6;
  if (blockIdx.x < 32) denom[blockIdx.x * 256 + t] = 0.f;
  if (blockIdx.x == 32 && t == 0) *cnt = 0u;

  const int k = blockIdx.x * 4 + wave;        // 0..4095 (pair index)
  const float4* pi = reinterpret_cast<const float4*>(emb_i + (size_t)k * DIM);
  const float4* pj = reinterpret_cast<const float4*>(emb_j + (size_t)k * DIM);

  float4 vi[4], vj[4];
#pragma unroll
  for (int q = 0; q < 4; ++q) vi[q] = pi[lane + 64 * q];
#pragma unroll
  for (int q = 0; q < 4; ++q) vj[q] = pj[lane + 64 * q];

  float ssi = 0.f, ssj = 0.f, dot = 0.f;
#pragma unroll
  for (int q = 0; q < 4; ++q) {
    ssi += vi[q].x * vi[q].x + vi[q].y * vi[q].y + vi[q].z * vi[q].z + vi[q].w * vi[q].w;
    ssj += vj[q].x * vj[q].x + vj[q].y * vj[q].y + vj[q].z * vj[q].z + vj[q].w * vj[q].w;
    dot += vi[q].x * vj[q].x + vi[q].y * vj[q].y + vi[q].z * vj[q].z + vi[q].w * vj[q].w;
  }
#pragma unroll
  for (int o = 32; o; o >>= 1) {
    ssi += __shfl_xor(ssi, o, 64);
    ssj += __shfl_xor(ssj, o, 64);
    dot += __shfl_xor(dot, o, 64);
  }
  const float invi = 1.0f / fmaxf(sqrtf(ssi), 1e-12f);
  const float invj = 1.0f / fmaxf(sqrtf(ssj), 1e-12f);

  uint32_t* poi = reinterpret_cast<uint32_t*>(reps + (size_t)k * DIM);
  uint32_t* poj = reinterpret_cast<uint32_t*>(reps + (size_t)(k + NROWS) * DIM);
#pragma unroll
  for (int q = 0; q < 4; ++q) {
    int di = __builtin_amdgcn_cvt_pk_fp8_f32(vi[q].x * invi, vi[q].y * invi, 0, false);
    di     = __builtin_amdgcn_cvt_pk_fp8_f32(vi[q].z * invi, vi[q].w * invi, di, true);
    int dj = __builtin_amdgcn_cvt_pk_fp8_f32(vj[q].x * invj, vj[q].y * invj, 0, false);
    dj     = __builtin_amdgcn_cvt_pk_fp8_f32(vj[q].z * invj, vj[q].w * invj, dj, true);
    poi[lane + 64 * q] = (uint32_t)di;
    poj[lane + 64 * q] = (uint32_t)dj;
  }
  if (lane == 0) pos[k] = dot * invi * invj;   // positive-pair cosine, fp32
}

// ---- kernel 2: fused sim-GEMM (MX-fp8) + exp + row/col sums, upper tri -----
// R16 = R15 with __launch_bounds__ REMOVED. R14/R15 post-mortem: with
// launch_bounds(512,{1,2}) the allocator capped at 128 VGPR (both args gave
// byte-identical codegen); acc[8][4] alone is 128 -> whole accumulator in
// scratch (WRITE 518MB, FETCH 840MB, 419us). Without launch_bounds this
// toolchain allocates freely (guide: 164 VGPR @256thr, 249 VGPR @512thr) and
// LDS (130.5KB) already limits occupancy to 1 blk/CU, so the bound buys
// nothing. Demand ~200-240 fits the unified 512-reg file at 2 waves/SIMD.
// Byte-rate theory unchanged: 256x256 tile (BK=128) stages 270MB total
// (0.667x of R9's 405MB @ 6.03 TB/s measured) -> predicted ~45-60us.
// 528 square tiles over upper tri (0<=bm<=bn<=31); 528=8*66 exact XCD remap.
// dbuf LDS (128KB) + counted vmcnt(8) + raw barriers; 8 waves as 2x4;
// per wave 8x4 grid of 16x16x128 scaled MFMAs per K-step. Swizzle scheme
// verified R6/R7; C/D col=lane&15,row=quad*4+reg.
__global__ void simsum_kernel(
    const uint8_t* __restrict__ reps, float* __restrict__ denom,
    const float* __restrict__ pos, unsigned int* __restrict__ cnt,
    float* __restrict__ out) {
  __shared__ __align__(16) uint8_t lA[2][256 * 128];  // 64 KB
  __shared__ __align__(16) uint8_t lB[2][256 * 128];  // 64 KB
  __shared__ float dl[256];   // row-side partial sums
  __shared__ float cl[256];   // col-side partial sums
  __shared__ unsigned int is_last;

  const int t    = threadIdx.x;
  const int lane = t & 63;
  const int wave = t >> 6;         // 0..7
  const int wm   = wave >> 2;      // wave row 0..1 (128-row strip)
  const int wn   = wave & 3;       // wave col 0..3 (64-col strip)

  // XCD-contiguous tile id (528 = 8*66, exact), then unrank upper triangle:
  // f(bm) = bm*(65-bm)/2 tiles precede row-block bm.
  const int ridx = ((blockIdx.x & 7) * 66) + (blockIdx.x >> 3);  // 0..527
  int bm = (int)(32.5f - sqrtf(1056.25f - 2.0f * (float)ridx));
  if (bm < 0) bm = 0;
  if (bm > 31) bm = 31;
  while (bm < 31 && (bm + 1) * (65 - (bm + 1)) / 2 <= ridx) ++bm;
  while (bm > 0 && bm * (65 - bm) / 2 > ridx) --bm;
  const int bn = bm + (ridx - bm * (65 - bm) / 2);   // bm..31

  const uint8_t* gA = reps + (size_t)bm * 256 * DIM;
  const uint8_t* gB = reps + (size_t)bn * 256 * DIM;

  // staging: thread t -> row q*64 + rr (rr=t>>3), 16B half-slot s16=t&7.
  // 32B chunk c32 = (s16>>1)^(rr&3); src byte = c32*32 + (s16&1)*16.
  const int rr  = t >> 3;                                      // 0..63
  const int swz = ((((t >> 1) & 3) ^ (rr & 3)) << 5) | ((t & 1) << 4);

  // ---- prologue: issue stage(0) into buf0; overlap VALU setup under it ----
#pragma unroll
  for (int q = 0; q < 4; ++q)
    gload16(gA + (size_t)(q * 64 + rr) * DIM + swz, lA[0] + q * 8192 + t * 16);
#pragma unroll
  for (int q = 0; q < 4; ++q)
    gload16(gB + (size_t)(q * 64 + rr) * DIM + swz, lB[0] + q * 8192 + t * 16);

  // zero partial-sum buffers (visibility covered by the K-loop barriers)
  if (t < 256) dl[t] = 0.f;
  else         cl[t - 256] = 0.f;

  floatx4 acc[8][4];
#pragma unroll
  for (int i = 0; i < 8; ++i)
#pragma unroll
    for (int j = 0; j < 4; ++j) acc[i][j] = floatx4{0.f, 0.f, 0.f, 0.f};

  const int mrow = lane & 15;        // fragment row select
  const int quad = lane >> 4;        // k block 0..3 (32 bytes each)
  const int soff = (quad ^ (mrow & 3)) << 5;   // 32B slot of this lane's chunk

#pragma unroll
  for (int k0 = 0; k0 < DIM; k0 += 128) {
    const int cur = (k0 >> 7) & 1;
    const int nxt = cur ^ 1;

    // 1) issue next tile's 8 staging loads (stay in flight across barriers;
    //    queue FIFO behind tile-t's, so they don't delay its completion)
    if (k0 + 128 < DIM) {
#pragma unroll
      for (int q = 0; q < 4; ++q)
        gload16(gA + (size_t)(q * 64 + rr) * DIM + (k0 + 128) + swz,
                lA[nxt] + q * 8192 + t * 16);
#pragma unroll
      for (int q = 0; q < 4; ++q)
        gload16(gB + (size_t)(q * 64 + rr) * DIM + (k0 + 128) + swz,
                lB[nxt] + q * 8192 + t * 16);
    }
    __builtin_amdgcn_sched_barrier(0);

    // 2) counted wait: tile-t's 8 loads landed; tile-(t+1)'s 8 stay in
    //    flight (vmcnt never 0 mid-loop).
    if (k0 + 128 < DIM) asm volatile("s_waitcnt vmcnt(8)" ::: "memory");
    else                asm volatile("s_waitcnt vmcnt(0)" ::: "memory");
    __builtin_amdgcn_s_barrier();      // raw: no implicit drain
    __builtin_amdgcn_sched_barrier(0);

    // 3) fragments + 32 MFMAs from current buffer
    F8 fb[4];
#pragma unroll
    for (int nt = 0; nt < 4; ++nt) {
      const uint8_t* pb = lB[cur] + (wn * 64 + nt * 16 + mrow) * 128 + soff;
      fb[nt].v4[0] = *reinterpret_cast<const intx4*>(pb);
      fb[nt].v4[1] = *reinterpret_cast<const intx4*>(pb + 16);
    }
    __builtin_amdgcn_s_setprio(1);
#pragma unroll
    for (int mt = 0; mt < 8; ++mt) {
      F8 fa;
      const uint8_t* pa = lA[cur] + (wm * 128 + mt * 16 + mrow) * 128 + soff;
      fa.v4[0] = *reinterpret_cast<const intx4*>(pa);
      fa.v4[1] = *reinterpret_cast<const intx4*>(pa + 16);
#pragma unroll
      for (int nt = 0; nt < 4; ++nt)
        acc[mt][nt] = __builtin_amdgcn_mfma_scale_f32_16x16x128_f8f6f4(
            fa.v8, fb[nt].v8, acc[mt][nt], 0, 0, 0, SCALE1, 0, SCALE1);
    }
    __builtin_amdgcn_s_setprio(0);
    __builtin_amdgcn_sched_barrier(0);

    // 4) all waves done reading buf[cur] before anyone stages over it next
    //    step (ds_reads retired before each wave's last MFMA issued).
    __builtin_amdgcn_s_barrier();
  }

  const bool doCol = (bn > bm);   // off-diagonal tile: add mirrored col-sums

  // exp in-place: acc now holds e = exp(sim/T)
#pragma unroll
  for (int mt = 0; mt < 8; ++mt)
#pragma unroll
    for (int nt = 0; nt < 4; ++nt)
#pragma unroll
      for (int r = 0; r < 4; ++r)
        acc[mt][nt][r] = __expf(acc[mt][nt][r] * INV_T);

  // row-sums: C/D layout (16x16): col=lane&15, row=quad*4+r
#pragma unroll
  for (int mt = 0; mt < 8; ++mt) {
#pragma unroll
    for (int r = 0; r < 4; ++r) {
      float s = acc[mt][0][r] + acc[mt][1][r] + acc[mt][2][r] + acc[mt][3][r];
      s += __shfl_xor(s, 1, 64);
      s += __shfl_xor(s, 2, 64);
      s += __shfl_xor(s, 4, 64);
      s += __shfl_xor(s, 8, 64);
      if ((lane & 15) == 0)
        atomicAdd(&dl[wm * 128 + mt * 16 + quad * 4 + r], s);
    }
  }

  // col-sums (mirror rows), strictly-off-diagonal tiles only
  if (doCol) {
#pragma unroll
    for (int nt = 0; nt < 4; ++nt) {
      float c = 0.f;
#pragma unroll
      for (int mt = 0; mt < 8; ++mt)
#pragma unroll
        for (int r = 0; r < 4; ++r) c += acc[mt][nt][r];
      c += __shfl_xor(c, 16, 64);
      c += __shfl_xor(c, 32, 64);
      if (quad == 0)
        atomicAdd(&cl[wn * 64 + nt * 16 + mrow], c);
    }
  }
  __syncthreads();
  if (t < 256) {
    atomicAdd(&denom[bm * 256 + t], dl[t]);
  } else if (doCol) {
    atomicAdd(&denom[bn * 256 + (t - 256)], cl[t - 256]);
  }
  // __syncthreads drains vmcnt(0): this block's device-scope denom atomics
  // are complete at the coherence point before the counter bump below.
  __syncthreads();
  if (t == 0)
    is_last = (__hip_atomic_fetch_add(cnt, 1u, __ATOMIC_RELAXED,
                                      __HIP_MEMORY_SCOPE_AGENT) == NT - 1)
                  ? 1u : 0u;
  __syncthreads();
  if (is_last) {
    float v = 0.f;
#pragma unroll
    for (int i = 0; i < TWON / 512; ++i) {
      float d = __hip_atomic_load(&denom[i * 512 + t], __ATOMIC_RELAXED,
                                  __HIP_MEMORY_SCOPE_AGENT);
      v += __logf(d - EXP_DIAG);
    }
    float p = 0.f;
#pragma unroll
    for (int i = 0; i < NROWS / 512; ++i)
      p += pos[i * 512 + t];
    v -= 4.0f * p;
#pragma unroll
    for (int o = 32; o; o >>= 1) v += __shfl_down(v, o, 64);
    if ((t & 63) == 0) dl[t >> 6] = v;
    __syncthreads();
    if (t == 0) {
      float tot = 0.f;
#pragma unroll
      for (int w = 0; w < 8; ++w) tot += dl[w];
      out[0] = tot * (1.0f / 8192.0f);
    }
  }
}

extern "C" void kernel_launch(void* const* d_in, const int* in_sizes, int n_in,
                              void* d_out, int out_size, void* d_ws, size_t ws_size,
                              hipStream_t stream) {
  const float* emb_i = (const float*)d_in[0];
  const float* emb_j = (const float*)d_in[1];
  float* out = (float*)d_out;

  uint8_t* reps = (uint8_t*)d_ws;                                  // 8.39 MB fp8
  float* denom  = (float*)((char*)d_ws + (size_t)TWON * DIM);      // 32 KB
  float* pos    = denom + TWON;                                    // 16 KB
  unsigned int* cnt = (unsigned int*)(pos + NROWS);

  normpos_kernel<<<1024, 256, 0, stream>>>(emb_i, emb_j, reps, denom, pos, cnt);
  simsum_kernel<<<NT, 512, 0, stream>>>(reps, denom, pos, cnt, out);
}

// Round 6
// 653.852 us; speedup vs baseline: 1.1573x; 1.1573x over previous
//
#include <hip/hip_runtime.h>
#include <cstdint>
#include <cstddef>

#define NROWS 4096
#define DIM   1024            // elements per row; also BYTES per fp8 row
#define TWON  8192
#define INV_T 2.0f
// exp(2.0) = exp(sim_rr / T) for the masked diagonal (rows are unit-norm)
#define EXP_DIAG 7.38905609893065f
#define NT    528             // # of 256x256 tiles covering the upper triangle
#define SCALE1 0x7F7F7F7F     // 4x E8M0 unity scales (127 -> 2^0)

typedef float floatx4 __attribute__((ext_vector_type(4)));
typedef int   intx4   __attribute__((ext_vector_type(4)));
typedef int   intx8   __attribute__((ext_vector_type(8)));

union F8 { intx8 v8; intx4 v4[2]; };

__device__ __forceinline__ void gload16(const uint8_t* g, uint8_t* l) {
  __builtin_amdgcn_global_load_lds(
      (const __attribute__((address_space(1))) void*)g,
      (__attribute__((address_space(3))) void*)l,
      16, 0, 0);
}

// -- kernel 1: normalize -> fp8 reps, fp32 pos dot, zero denom/cnt ------------
// UNCHANGED so the total-time delta attributes to simsum.
__global__ __launch_bounds__(256) void normpos_kernel(
    const float* __restrict__ emb_i, const float* __restrict__ emb_j,
    uint8_t* __restrict__ reps, float* __restrict__ denom,
    float* __restrict__ pos, unsigned int* __restrict__ cnt) {
  const int t    = threadIdx.x;
  const int lane = t & 63;
  const int wave = t >> 6;
  if (blockIdx.x < 32) denom[blockIdx.x * 256 + t] = 0.f;
  if (blockIdx.x == 32 && t == 0) *cnt = 0u;

  const int k = blockIdx.x * 4 + wave;        // 0..4095 (pair index)
  const float4* pi = reinterpret_cast<const float4*>(emb_i + (size_t)k * DIM);
  const float4* pj = reinterpret_cast<const float4*>(emb_j + (size_t)k * DIM);

  float4 vi[4], vj[4];
#pragma unroll
  for (int q = 0; q < 4; ++q) vi[q] = pi[lane + 64 * q];
#pragma unroll
  for (int q = 0; q < 4; ++q) vj[q] = pj[lane + 64 * q];

  float ssi = 0.f, ssj = 0.f, dot = 0.f;
#pragma unroll
  for (int q = 0; q < 4; ++q) {
    ssi += vi[q].x * vi[q].x + vi[q].y * vi[q].y + vi[q].z * vi[q].z + vi[q].w * vi[q].w;
    ssj += vj[q].x * vj[q].x + vj[q].y * vj[q].y + vj[q].z * vj[q].z + vj[q].w * vj[q].w;
    dot += vi[q].x * vj[q].x + vi[q].y * vj[q].y + vi[q].z * vj[q].z + vi[q].w * vj[q].w;
  }
#pragma unroll
  for (int o = 32; o; o >>= 1) {
    ssi += __shfl_xor(ssi, o, 64);
    ssj += __shfl_xor(ssj, o, 64);
    dot += __shfl_xor(dot, o, 64);
  }
  const float invi = 1.0f / fmaxf(sqrtf(ssi), 1e-12f);
  const float invj = 1.0f / fmaxf(sqrtf(ssj), 1e-12f);

  uint32_t* poi = reinterpret_cast<uint32_t*>(reps + (size_t)k * DIM);
  uint32_t* poj = reinterpret_cast<uint32_t*>(reps + (size_t)(k + NROWS) * DIM);
#pragma unroll
  for (int q = 0; q < 4; ++q) {
    int di = __builtin_amdgcn_cvt_pk_fp8_f32(vi[q].x * invi, vi[q].y * invi, 0, false);
    di     = __builtin_amdgcn_cvt_pk_fp8_f32(vi[q].z * invi, vi[q].w * invi, di, true);
    int dj = __builtin_amdgcn_cvt_pk_fp8_f32(vj[q].x * invj, vj[q].y * invj, 0, false);
    dj     = __builtin_amdgcn_cvt_pk_fp8_f32(vj[q].z * invj, vj[q].w * invj, dj, true);
    poi[lane + 64 * q] = (uint32_t)di;
    poj[lane + 64 * q] = (uint32_t)dj;
  }
  if (lane == 0) pos[k] = dot * invi * invj;   // positive-pair cosine, fp32
}

// ---- kernel 2: fused sim-GEMM (MX-fp8) + exp + row/col sums, upper tri -----
// R17: 256x256 tile via 1024 threads, keeping R9's per-thread register shape.
// R14-R16 post-mortem: acc[8][4] (128 floats/thread) spills under EVERY
// launch_bounds variant on this toolchain (WRITE 518-728MB). R9's shape --
// acc[4][4]=64 + one held frag array + one streamed frag, launch_bounds(_,4)
// -- is the proven-allocatable profile, so get the big tile from MORE
// THREADS instead: 16 waves as 4x4, each wave owns 64x64 of 256x256.
// Byte-rate law (R9/R12/R13 invariant): staged bytes land at ~10 B/cy/CU
// regardless of schedule -> lever is total bytes. 256x256 stages 270MB
// (0.667x of R9's 405MB) -> predicted simsum ~45-52us.
// 528 tiles over upper tri (0<=bm<=bn<=31); 528=8*66 exact XCD remap.
// dbuf LDS 128KB + counted vmcnt(4) + raw barriers (4 gloads/thread/step);
// 1 blk/CU, 4 waves/SIMD self-overlap. Swizzle scheme verified R6/R7
// (key=row&3, rr=t>>3 keeps row&3=rr&3 at 128-row rounds);
// C/D col=lane&15,row=quad*4+reg.
__global__ __launch_bounds__(1024, 4) void simsum_kernel(
    const uint8_t* __restrict__ reps, float* __restrict__ denom,
    const float* __restrict__ pos, unsigned int* __restrict__ cnt,
    float* __restrict__ out) {
  __shared__ __align__(16) uint8_t lA[2][256 * 128];  // 64 KB
  __shared__ __align__(16) uint8_t lB[2][256 * 128];  // 64 KB
  __shared__ float dl[256];   // row-side partial sums
  __shared__ float cl[256];   // col-side partial sums
  __shared__ unsigned int is_last;

  const int t    = threadIdx.x;
  const int lane = t & 63;
  const int wave = t >> 6;         // 0..15
  const int wr   = wave >> 2;      // wave row 0..3 (64-row strip)
  const int wc   = wave & 3;       // wave col 0..3 (64-col strip)

  // XCD-contiguous tile id (528 = 8*66, exact), then unrank upper triangle:
  // f(bm) = bm*(65-bm)/2 tiles precede row-block bm.
  const int ridx = ((blockIdx.x & 7) * 66) + (blockIdx.x >> 3);  // 0..527
  int bm = (int)(32.5f - sqrtf(1056.25f - 2.0f * (float)ridx));
  if (bm < 0) bm = 0;
  if (bm > 31) bm = 31;
  while (bm < 31 && (bm + 1) * (65 - (bm + 1)) / 2 <= ridx) ++bm;
  while (bm > 0 && bm * (65 - bm) / 2 > ridx) --bm;
  const int bn = bm + (ridx - bm * (65 - bm) / 2);   // bm..31

  const uint8_t* gA = reps + (size_t)bm * 256 * DIM;
  const uint8_t* gB = reps + (size_t)bn * 256 * DIM;

  // staging: 1024 thr, 4 rounds of 16KB. Round covers 128 rows x 8 slots.
  // thread t -> row rr=t>>3 (0..127), 16B half-slot s=t&7.
  // 32B chunk c32 = (s>>1)^(rr&3); src byte = c32*32 + (s&1)*16.
  const int rr  = t >> 3;                                      // 0..127
  const int swz = ((((t >> 1) & 3) ^ (rr & 3)) << 5) | ((t & 1) << 4);

  // ---- prologue: issue stage(0) into buf0; overlap VALU setup under it ----
#pragma unroll
  for (int q = 0; q < 2; ++q)
    gload16(gA + (size_t)(q * 128 + rr) * DIM + swz, lA[0] + q * 16384 + t * 16);
#pragma unroll
  for (int q = 0; q < 2; ++q)
    gload16(gB + (size_t)(q * 128 + rr) * DIM + swz, lB[0] + q * 16384 + t * 16);

  // zero partial-sum buffers (visibility covered by the K-loop barriers)
  if (t < 256) dl[t] = 0.f;
  else if (t < 512) cl[t - 256] = 0.f;

  floatx4 acc[4][4];
#pragma unroll
  for (int i = 0; i < 4; ++i)
#pragma unroll
    for (int j = 0; j < 4; ++j) acc[i][j] = floatx4{0.f, 0.f, 0.f, 0.f};

  const int mrow = lane & 15;        // fragment row select
  const int quad = lane >> 4;        // k block 0..3 (32 bytes each)
  const int soff = (quad ^ (mrow & 3)) << 5;   // 32B slot of this lane's chunk

#pragma unroll
  for (int k0 = 0; k0 < DIM; k0 += 128) {
    const int cur = (k0 >> 7) & 1;
    const int nxt = cur ^ 1;

    // 1) issue next tile's 4 staging loads (stay in flight across barriers)
    if (k0 + 128 < DIM) {
#pragma unroll
      for (int q = 0; q < 2; ++q)
        gload16(gA + (size_t)(q * 128 + rr) * DIM + (k0 + 128) + swz,
                lA[nxt] + q * 16384 + t * 16);
#pragma unroll
      for (int q = 0; q < 2; ++q)
        gload16(gB + (size_t)(q * 128 + rr) * DIM + (k0 + 128) + swz,
                lB[nxt] + q * 16384 + t * 16);
    }
    __builtin_amdgcn_sched_barrier(0);

    // 2) counted wait: tile-t's 4 loads landed; tile-(t+1)'s 4 stay in
    //    flight (vmcnt never 0 mid-loop).
    if (k0 + 128 < DIM) asm volatile("s_waitcnt vmcnt(4)" ::: "memory");
    else                asm volatile("s_waitcnt vmcnt(0)" ::: "memory");
    __builtin_amdgcn_s_barrier();      // raw: no implicit drain
    __builtin_amdgcn_sched_barrier(0);

    // 3) hold A-frags (fa[4], 32 regs), stream B-frags (8 regs); 16 MFMAs
    F8 fa[4];
#pragma unroll
    for (int mt = 0; mt < 4; ++mt) {
      const uint8_t* pa = lA[cur] + (wr * 64 + mt * 16 + mrow) * 128 + soff;
      fa[mt].v4[0] = *reinterpret_cast<const intx4*>(pa);
      fa[mt].v4[1] = *reinterpret_cast<const intx4*>(pa + 16);
    }
    __builtin_amdgcn_s_setprio(1);
#pragma unroll
    for (int nt = 0; nt < 4; ++nt) {
      F8 fb;
      const uint8_t* pb = lB[cur] + (wc * 64 + nt * 16 + mrow) * 128 + soff;
      fb.v4[0] = *reinterpret_cast<const intx4*>(pb);
      fb.v4[1] = *reinterpret_cast<const intx4*>(pb + 16);
#pragma unroll
      for (int mt = 0; mt < 4; ++mt)
        acc[mt][nt] = __builtin_amdgcn_mfma_scale_f32_16x16x128_f8f6f4(
            fa[mt].v8, fb.v8, acc[mt][nt], 0, 0, 0, SCALE1, 0, SCALE1);
    }
    __builtin_amdgcn_s_setprio(0);
    __builtin_amdgcn_sched_barrier(0);

    // 4) all waves done reading buf[cur] before anyone stages over it next
    //    step (ds_reads retired before each wave's last MFMA issued).
    __builtin_amdgcn_s_barrier();
  }

  const bool doCol = (bn > bm);   // off-diagonal tile: add mirrored col-sums

  // exp in-place: acc now holds e = exp(sim/T)
#pragma unroll
  for (int mt = 0; mt < 4; ++mt)
#pragma unroll
    for (int nt = 0; nt < 4; ++nt)
#pragma unroll
      for (int r = 0; r < 4; ++r)
        acc[mt][nt][r] = __expf(acc[mt][nt][r] * INV_T);

  // row-sums: C/D layout (16x16): col=lane&15, row=quad*4+r
#pragma unroll
  for (int mt = 0; mt < 4; ++mt) {
#pragma unroll
    for (int r = 0; r < 4; ++r) {
      float s = acc[mt][0][r] + acc[mt][1][r] + acc[mt][2][r] + acc[mt][3][r];
      s += __shfl_xor(s, 1, 64);
      s += __shfl_xor(s, 2, 64);
      s += __shfl_xor(s, 4, 64);
      s += __shfl_xor(s, 8, 64);
      if ((lane & 15) == 0)
        atomicAdd(&dl[wr * 64 + mt * 16 + quad * 4 + r], s);
    }
  }

  // col-sums (mirror rows), strictly-off-diagonal tiles only
  if (doCol) {
#pragma unroll
    for (int nt = 0; nt < 4; ++nt) {
      float c = 0.f;
#pragma unroll
      for (int mt = 0; mt < 4; ++mt)
#pragma unroll
        for (int r = 0; r < 4; ++r) c += acc[mt][nt][r];
      c += __shfl_xor(c, 16, 64);
      c += __shfl_xor(c, 32, 64);
      if (quad == 0)
        atomicAdd(&cl[wc * 64 + nt * 16 + mrow], c);
    }
  }
  __syncthreads();
  if (t < 256) {
    atomicAdd(&denom[bm * 256 + t], dl[t]);
  } else if (t < 512 && doCol) {
    atomicAdd(&denom[bn * 256 + (t - 256)], cl[t - 256]);
  }
  // __syncthreads drains vmcnt(0): this block's device-scope denom atomics
  // are complete at the coherence point before the counter bump below.
  __syncthreads();
  if (t == 0)
    is_last = (__hip_atomic_fetch_add(cnt, 1u, __ATOMIC_RELAXED,
                                      __HIP_MEMORY_SCOPE_AGENT) == NT - 1)
                  ? 1u : 0u;
  __syncthreads();
  if (is_last) {
    float v = 0.f;
#pragma unroll
    for (int i = 0; i < TWON / 1024; ++i) {
      float d = __hip_atomic_load(&denom[i * 1024 + t], __ATOMIC_RELAXED,
                                  __HIP_MEMORY_SCOPE_AGENT);
      v += __logf(d - EXP_DIAG);
    }
    float p = 0.f;
#pragma unroll
    for (int i = 0; i < NROWS / 1024; ++i)
      p += pos[i * 1024 + t];
    v -= 4.0f * p;
#pragma unroll
    for (int o = 32; o; o >>= 1) v += __shfl_down(v, o, 64);
    if ((t & 63) == 0) dl[t >> 6] = v;
    __syncthreads();
    if (t == 0) {
      float tot = 0.f;
#pragma unroll
      for (int w = 0; w < 16; ++w) tot += dl[w];
      out[0] = tot * (1.0f / 8192.0f);
    }
  }
}

extern "C" void kernel_launch(void* const* d_in, const int* in_sizes, int n_in,
                              void* d_out, int out_size, void* d_ws, size_t ws_size,
                              hipStream_t stream) {
  const float* emb_i = (const float*)d_in[0];
  const float* emb_j = (const float*)d_in[1];
  float* out = (float*)d_out;

  uint8_t* reps = (uint8_t*)d_ws;                                  // 8.39 MB fp8
  float* denom  = (float*)((char*)d_ws + (size_t)TWON * DIM);      // 32 KB
  float* pos    = denom + TWON;                                    // 16 KB
  unsigned int* cnt = (unsigned int*)(pos + NROWS);

  normpos_kernel<<<1024, 256, 0, stream>>>(emb_i, emb_j, reps, denom, pos, cnt);
  simsum_kernel<<<NT, 1024, 0, stream>>>(reps, denom, pos, cnt, out);
}

// Round 7
// 140.580 us; speedup vs baseline: 5.3825x; 4.6511x over previous
//
#include <hip/hip_runtime.h>
#include <cstdint>
#include <cstddef>

#define NROWS 4096
#define DIM   1024            // elements per row; also BYTES per fp8 row
#define TWON  8192
#define INV_T 2.0f
// exp(2.0) = exp(sim_rr / T) for the masked diagonal (rows are unit-norm)
#define EXP_DIAG 7.38905609893065f
#define NT    528             // # of 256x256 tiles covering the upper triangle
#define SCALE1 0x7F7F7F7F     // 4x E8M0 unity scales (127 -> 2^0)

typedef float floatx4 __attribute__((ext_vector_type(4)));
typedef int   intx4   __attribute__((ext_vector_type(4)));
typedef int   intx8   __attribute__((ext_vector_type(8)));

union F8 { intx8 v8; intx4 v4[2]; };

__device__ __forceinline__ void gload16(const uint8_t* g, uint8_t* l) {
  __builtin_amdgcn_global_load_lds(
      (const __attribute__((address_space(1))) void*)g,
      (__attribute__((address_space(3))) void*)l,
      16, 0, 0);
}

// -- kernel 1: normalize -> fp8 reps, fp32 pos dot, zero denom/cnt ------------
// UNCHANGED so the total-time delta attributes to simsum.
__global__ __launch_bounds__(256) void normpos_kernel(
    const float* __restrict__ emb_i, const float* __restrict__ emb_j,
    uint8_t* __restrict__ reps, float* __restrict__ denom,
    float* __restrict__ pos, unsigned int* __restrict__ cnt) {
  const int t    = threadIdx.x;
  const int lane = t & 63;
  const int wave = t >> 6;
  if (blockIdx.x < 32) denom[blockIdx.x * 256 + t] = 0.f;
  if (blockIdx.x == 32 && t == 0) *cnt = 0u;

  const int k = blockIdx.x * 4 + wave;        // 0..4095 (pair index)
  const float4* pi = reinterpret_cast<const float4*>(emb_i + (size_t)k * DIM);
  const float4* pj = reinterpret_cast<const float4*>(emb_j + (size_t)k * DIM);

  float4 vi[4], vj[4];
#pragma unroll
  for (int q = 0; q < 4; ++q) vi[q] = pi[lane + 64 * q];
#pragma unroll
  for (int q = 0; q < 4; ++q) vj[q] = pj[lane + 64 * q];

  float ssi = 0.f, ssj = 0.f, dot = 0.f;
#pragma unroll
  for (int q = 0; q < 4; ++q) {
    ssi += vi[q].x * vi[q].x + vi[q].y * vi[q].y + vi[q].z * vi[q].z + vi[q].w * vi[q].w;
    ssj += vj[q].x * vj[q].x + vj[q].y * vj[q].y + vj[q].z * vj[q].z + vj[q].w * vj[q].w;
    dot += vi[q].x * vj[q].x + vi[q].y * vj[q].y + vi[q].z * vj[q].z + vi[q].w * vj[q].w;
  }
#pragma unroll
  for (int o = 32; o; o >>= 1) {
    ssi += __shfl_xor(ssi, o, 64);
    ssj += __shfl_xor(ssj, o, 64);
    dot += __shfl_xor(dot, o, 64);
  }
  const float invi = 1.0f / fmaxf(sqrtf(ssi), 1e-12f);
  const float invj = 1.0f / fmaxf(sqrtf(ssj), 1e-12f);

  uint32_t* poi = reinterpret_cast<uint32_t*>(reps + (size_t)k * DIM);
  uint32_t* poj = reinterpret_cast<uint32_t*>(reps + (size_t)(k + NROWS) * DIM);
#pragma unroll
  for (int q = 0; q < 4; ++q) {
    int di = __builtin_amdgcn_cvt_pk_fp8_f32(vi[q].x * invi, vi[q].y * invi, 0, false);
    di     = __builtin_amdgcn_cvt_pk_fp8_f32(vi[q].z * invi, vi[q].w * invi, di, true);
    int dj = __builtin_amdgcn_cvt_pk_fp8_f32(vj[q].x * invj, vj[q].y * invj, 0, false);
    dj     = __builtin_amdgcn_cvt_pk_fp8_f32(vj[q].z * invj, vj[q].w * invj, dj, true);
    poi[lane + 64 * q] = (uint32_t)di;
    poj[lane + 64 * q] = (uint32_t)dj;
  }
  if (lane == 0) pos[k] = dot * invi * invj;   // positive-pair cosine, fp32
}

// ---- kernel 2: fused sim-GEMM (MX-fp8) + exp + row/col sums, upper tri -----
// R18 = R17 + "#pragma unroll 1" on the K-loop. R17 post-mortem: the
// per-thread register shape (acc[4][4]+fa[4]+fb) is R9's proven profile,
// but FULL unroll of 8 iters x 4 gload_lds hoists ~32 64-bit global
// addresses -> allocator (128-reg budget at 4 waves/EU) dumps acc to
// scratch (WRITE 805MB). R9 used unroll 1 and allocated cleanly; R13's
// full unroll survived only because its (512,2) budget was 256.
// Geometry (verified correct in R17, absmax=0): 256x256 tile via 1024 thr,
// 16 waves as 4x4, each wave 64x64 out = 4x4 grid of 16x16x128 MX MFMAs.
// Byte lever: 270MB total staged (0.667x of R9's 405MB). dbuf LDS 128KB,
// counted vmcnt(4), raw barriers, 1 blk/CU, 4 waves/SIMD self-overlap.
// Swizzle verified R6/R7; C/D col=lane&15,row=quad*4+reg.
__global__ __launch_bounds__(1024, 4) void simsum_kernel(
    const uint8_t* __restrict__ reps, float* __restrict__ denom,
    const float* __restrict__ pos, unsigned int* __restrict__ cnt,
    float* __restrict__ out) {
  __shared__ __align__(16) uint8_t lA[2][256 * 128];  // 64 KB
  __shared__ __align__(16) uint8_t lB[2][256 * 128];  // 64 KB
  __shared__ float dl[256];   // row-side partial sums
  __shared__ float cl[256];   // col-side partial sums
  __shared__ unsigned int is_last;

  const int t    = threadIdx.x;
  const int lane = t & 63;
  const int wave = t >> 6;         // 0..15
  const int wr   = wave >> 2;      // wave row 0..3 (64-row strip)
  const int wc   = wave & 3;       // wave col 0..3 (64-col strip)

  // XCD-contiguous tile id (528 = 8*66, exact), then unrank upper triangle:
  // f(bm) = bm*(65-bm)/2 tiles precede row-block bm.
  const int ridx = ((blockIdx.x & 7) * 66) + (blockIdx.x >> 3);  // 0..527
  int bm = (int)(32.5f - sqrtf(1056.25f - 2.0f * (float)ridx));
  if (bm < 0) bm = 0;
  if (bm > 31) bm = 31;
  while (bm < 31 && (bm + 1) * (65 - (bm + 1)) / 2 <= ridx) ++bm;
  while (bm > 0 && bm * (65 - bm) / 2 > ridx) --bm;
  const int bn = bm + (ridx - bm * (65 - bm) / 2);   // bm..31

  const uint8_t* gA = reps + (size_t)bm * 256 * DIM;
  const uint8_t* gB = reps + (size_t)bn * 256 * DIM;

  // staging: 1024 thr, 4 rounds of 16KB. Round covers 128 rows x 8 slots.
  // thread t -> row rr=t>>3 (0..127), 16B half-slot s=t&7.
  // 32B chunk c32 = (s>>1)^(rr&3); src byte = c32*32 + (s&1)*16.
  const int rr  = t >> 3;                                      // 0..127
  const int swz = ((((t >> 1) & 3) ^ (rr & 3)) << 5) | ((t & 1) << 4);

  // ---- prologue: issue stage(0) into buf0; overlap VALU setup under it ----
#pragma unroll
  for (int q = 0; q < 2; ++q)
    gload16(gA + (size_t)(q * 128 + rr) * DIM + swz, lA[0] + q * 16384 + t * 16);
#pragma unroll
  for (int q = 0; q < 2; ++q)
    gload16(gB + (size_t)(q * 128 + rr) * DIM + swz, lB[0] + q * 16384 + t * 16);

  // zero partial-sum buffers (visibility covered by the K-loop barriers)
  if (t < 256) dl[t] = 0.f;
  else if (t < 512) cl[t - 256] = 0.f;

  floatx4 acc[4][4];
#pragma unroll
  for (int i = 0; i < 4; ++i)
#pragma unroll
    for (int j = 0; j < 4; ++j) acc[i][j] = floatx4{0.f, 0.f, 0.f, 0.f};

  const int mrow = lane & 15;        // fragment row select
  const int quad = lane >> 4;        // k block 0..3 (32 bytes each)
  const int soff = (quad ^ (mrow & 3)) << 5;   // 32B slot of this lane's chunk

#pragma unroll 1
  for (int k0 = 0; k0 < DIM; k0 += 128) {
    const int cur = (k0 >> 7) & 1;
    const int nxt = cur ^ 1;

    // 1) issue next tile's 4 staging loads (stay in flight across barriers)
    if (k0 + 128 < DIM) {
#pragma unroll
      for (int q = 0; q < 2; ++q)
        gload16(gA + (size_t)(q * 128 + rr) * DIM + (k0 + 128) + swz,
                lA[nxt] + q * 16384 + t * 16);
#pragma unroll
      for (int q = 0; q < 2; ++q)
        gload16(gB + (size_t)(q * 128 + rr) * DIM + (k0 + 128) + swz,
                lB[nxt] + q * 16384 + t * 16);
    }
    __builtin_amdgcn_sched_barrier(0);

    // 2) counted wait: tile-t's 4 loads landed; tile-(t+1)'s 4 stay in
    //    flight (vmcnt never 0 mid-loop).
    if (k0 + 128 < DIM) asm volatile("s_waitcnt vmcnt(4)" ::: "memory");
    else                asm volatile("s_waitcnt vmcnt(0)" ::: "memory");
    __builtin_amdgcn_s_barrier();      // raw: no implicit drain
    __builtin_amdgcn_sched_barrier(0);

    // 3) hold A-frags (fa[4], 32 regs), stream B-frags (8 regs); 16 MFMAs
    F8 fa[4];
#pragma unroll
    for (int mt = 0; mt < 4; ++mt) {
      const uint8_t* pa = lA[cur] + (wr * 64 + mt * 16 + mrow) * 128 + soff;
      fa[mt].v4[0] = *reinterpret_cast<const intx4*>(pa);
      fa[mt].v4[1] = *reinterpret_cast<const intx4*>(pa + 16);
    }
    __builtin_amdgcn_s_setprio(1);
#pragma unroll
    for (int nt = 0; nt < 4; ++nt) {
      F8 fb;
      const uint8_t* pb = lB[cur] + (wc * 64 + nt * 16 + mrow) * 128 + soff;
      fb.v4[0] = *reinterpret_cast<const intx4*>(pb);
      fb.v4[1] = *reinterpret_cast<const intx4*>(pb + 16);
#pragma unroll
      for (int mt = 0; mt < 4; ++mt)
        acc[mt][nt] = __builtin_amdgcn_mfma_scale_f32_16x16x128_f8f6f4(
            fa[mt].v8, fb.v8, acc[mt][nt], 0, 0, 0, SCALE1, 0, SCALE1);
    }
    __builtin_amdgcn_s_setprio(0);
    __builtin_amdgcn_sched_barrier(0);

    // 4) all waves done reading buf[cur] before anyone stages over it next
    //    step (ds_reads retired before each wave's last MFMA issued).
    __builtin_amdgcn_s_barrier();
  }

  const bool doCol = (bn > bm);   // off-diagonal tile: add mirrored col-sums

  // exp in-place: acc now holds e = exp(sim/T)
#pragma unroll
  for (int mt = 0; mt < 4; ++mt)
#pragma unroll
    for (int nt = 0; nt < 4; ++nt)
#pragma unroll
      for (int r = 0; r < 4; ++r)
        acc[mt][nt][r] = __expf(acc[mt][nt][r] * INV_T);

  // row-sums: C/D layout (16x16): col=lane&15, row=quad*4+r
#pragma unroll
  for (int mt = 0; mt < 4; ++mt) {
#pragma unroll
    for (int r = 0; r < 4; ++r) {
      float s = acc[mt][0][r] + acc[mt][1][r] + acc[mt][2][r] + acc[mt][3][r];
      s += __shfl_xor(s, 1, 64);
      s += __shfl_xor(s, 2, 64);
      s += __shfl_xor(s, 4, 64);
      s += __shfl_xor(s, 8, 64);
      if ((lane & 15) == 0)
        atomicAdd(&dl[wr * 64 + mt * 16 + quad * 4 + r], s);
    }
  }

  // col-sums (mirror rows), strictly-off-diagonal tiles only
  if (doCol) {
#pragma unroll
    for (int nt = 0; nt < 4; ++nt) {
      float c = 0.f;
#pragma unroll
      for (int mt = 0; mt < 4; ++mt)
#pragma unroll
        for (int r = 0; r < 4; ++r) c += acc[mt][nt][r];
      c += __shfl_xor(c, 16, 64);
      c += __shfl_xor(c, 32, 64);
      if (quad == 0)
        atomicAdd(&cl[wc * 64 + nt * 16 + mrow], c);
    }
  }
  __syncthreads();
  if (t < 256) {
    atomicAdd(&denom[bm * 256 + t], dl[t]);
  } else if (t < 512 && doCol) {
    atomicAdd(&denom[bn * 256 + (t - 256)], cl[t - 256]);
  }
  // __syncthreads drains vmcnt(0): this block's device-scope denom atomics
  // are complete at the coherence point before the counter bump below.
  __syncthreads();
  if (t == 0)
    is_last = (__hip_atomic_fetch_add(cnt, 1u, __ATOMIC_RELAXED,
                                      __HIP_MEMORY_SCOPE_AGENT) == NT - 1)
                  ? 1u : 0u;
  __syncthreads();
  if (is_last) {
    float v = 0.f;
#pragma unroll
    for (int i = 0; i < TWON / 1024; ++i) {
      float d = __hip_atomic_load(&denom[i * 1024 + t], __ATOMIC_RELAXED,
                                  __HIP_MEMORY_SCOPE_AGENT);
      v += __logf(d - EXP_DIAG);
    }
    float p = 0.f;
#pragma unroll
    for (int i = 0; i < NROWS / 1024; ++i)
      p += pos[i * 1024 + t];
    v -= 4.0f * p;
#pragma unroll
    for (int o = 32; o; o >>= 1) v += __shfl_down(v, o, 64);
    if ((t & 63) == 0) dl[t >> 6] = v;
    __syncthreads();
    if (t == 0) {
      float tot = 0.f;
#pragma unroll
      for (int w = 0; w < 16; ++w) tot += dl[w];
      out[0] = tot * (1.0f / 8192.0f);
    }
  }
}

extern "C" void kernel_launch(void* const* d_in, const int* in_sizes, int n_in,
                              void* d_out, int out_size, void* d_ws, size_t ws_size,
                              hipStream_t stream) {
  const float* emb_i = (const float*)d_in[0];
  const float* emb_j = (const float*)d_in[1];
  float* out = (float*)d_out;

  uint8_t* reps = (uint8_t*)d_ws;                                  // 8.39 MB fp8
  float* denom  = (float*)((char*)d_ws + (size_t)TWON * DIM);      // 32 KB
  float* pos    = denom + TWON;                                    // 16 KB
  unsigned int* cnt = (unsigned int*)(pos + NROWS);

  normpos_kernel<<<1024, 256, 0, stream>>>(emb_i, emb_j, reps, denom, pos, cnt);
  simsum_kernel<<<NT, 1024, 0, stream>>>(reps, denom, pos, cnt, out);
}